// Round 4
// baseline (349.928 us; speedup 1.0000x reference)
//
#include <hip/hip_runtime.h>

// CostVolume via bf16 MFMA Gram band: cost[b,d,h,w] = (1/64)·G[w][w-d],
// G = L^T·R per (b,h), banded (0 <= d < 48). B=4 C=64 H=256 W=512 D=48.
//
// Round-7: DIRECT-GLOBAL fragments (no staging). Rounds 1-3 showed the
// stage->drain->pack->barrier->compute convoy caps load duty at ~4%
// (HBM pinned ~2 TB/s; occupancy/conflict/pipeline fixes all null; r3's
// reg-pipeline was compiler-defeated, VGPR=64 proves loads were sunk).
// A block's per-stage reuse set is ~22 KB -- L1/L2-resident -- so LDS
// staging buys nothing (guide common-mistake #7). Each MFMA fragment is
// now loaded straight from global: 8 scalar dword loads per lane at the
// (c,w) the MFMA layout wants (c=c0+8q+k, col fixed per lane), packed
// with the same RNE f2bf2 as the verified kernels (bit-identical math;
// L2 serves the ~3x R reuse). No main-loop barriers, no LDS writes: 160
// independent loads/lane that the compiler can hoist freely -> deep MLP.
// Epilogue unchanged (r2/r3-verified): LDS scratch scatter + cooperative
// full-128B-line nontemporal stores. LDS now only 12.4 KB.

#define BB 4
#define CC 64
#define HH 256
#define WW 512
#define DD 48
#define TW 128
#define ST 129         // epilogue scratch row stride (fp32)
#define NT 256

typedef short bf16x8 __attribute__((ext_vector_type(8)));
typedef float f32x4  __attribute__((ext_vector_type(4)));

// fp32 -> bf16 round-to-nearest-even, packed pair (lo in bits 15:0)
__device__ __forceinline__ unsigned int f2bf2(float lo, float hi) {
  unsigned int a = __float_as_uint(lo);
  unsigned int b = __float_as_uint(hi);
  a = (a + 0x7fffu + ((a >> 16) & 1u)) >> 16;
  b = (b + 0x7fffu + ((b >> 16) & 1u)) & 0xffff0000u;
  return a | b;
}

__global__ __launch_bounds__(NT, 4)
void cost_volume_mfma(const float* __restrict__ left,
                      const float* __restrict__ right,
                      float* __restrict__ out) {
  __shared__ __align__(16) float scr[24 * ST];   // epilogue scratch only

  const int w0   = blockIdx.x * TW;   // 0,128,256,384
  const int h    = blockIdx.y;
  const int b    = blockIdx.z;
  const int tid  = threadIdx.x;
  const int lane = tid & 63;
  const int wv   = tid >> 6;          // wave 0..3
  const int n16  = lane & 15;
  const int q    = lane >> 4;

  const size_t HWs     = (size_t)HH * WW;
  const size_t rowbase = (size_t)b * CC * HWs + (size_t)h * WW;

  // per-lane channel-block base (c = 8q + k), row h
  const float* Lp = left  + rowbase + (size_t)(8 * q) * HWs;
  const float* Rp = right + rowbase + (size_t)(8 * q) * HWs;

  f32x4 acc[2][4];
  #pragma unroll
  for (int i = 0; i < 2; ++i)
    #pragma unroll
    for (int t = 0; t < 4; ++t)
      acc[i][t] = (f32x4){0.f, 0.f, 0.f, 0.f};

  #pragma unroll
  for (int i = 0; i < 2; ++i) {
    const int u0 = 16 * wv + 64 * i;   // in-tile output col base
    const int cA = w0 + u0 + n16;      // A global col (this lane's row m)
    #pragma unroll
    for (int c0 = 0; c0 < CC; c0 += 32) {
      // ---- A fragment: L[c0+8q+k][cA], k = 0..7 (same element->lane map
      // as the LDS path: A.u[jj] = (c=2jj) | (c=2jj+1)<<16)
      float a[8];
      #pragma unroll
      for (int k = 0; k < 8; ++k)
        a[k] = Lp[(size_t)(c0 + k) * HWs + cA];
      union { unsigned int u[4]; bf16x8 v; } Af;
      #pragma unroll
      for (int jj = 0; jj < 4; ++jj)
        Af.u[jj] = f2bf2(a[2 * jj], a[2 * jj + 1]);

      #pragma unroll
      for (int t = 0; t < 4; ++t) {
        // ---- B fragment: R[c0+8q+k][cB]; cB<0 lanes supply exact zeros
        const int cB = cA + 16 * t - 48;
        float bb[8];
        #pragma unroll
        for (int k = 0; k < 8; ++k)
          bb[k] = (cB >= 0) ? Rp[(size_t)(c0 + k) * HWs + cB] : 0.f;
        union { unsigned int u[4]; bf16x8 v; } Bf;
        #pragma unroll
        for (int jj = 0; jj < 4; ++jj)
          Bf.u[jj] = f2bf2(bb[2 * jj], bb[2 * jj + 1]);

        acc[i][t] = __builtin_amdgcn_mfma_f32_16x16x32_bf16(Af.v, Bf.v,
                                                            acc[i][t], 0, 0, 0);
      }
    }
  }

  // ---- epilogue (r2/r3-verified): scratch scatter, 2 halves x 24 d-rows,
  // then cooperative full-128B-line nontemporal stores.
  const float scale = 1.0f / 64.0f;
  #pragma unroll 1
  for (int half = 0; half < 2; ++half) {
    const int dbase = 24 * half;
    if (half) __syncthreads();   // half-0 E2 reads done before overwrite
    // E1: scatter acc -> scr[d - dbase][u0 + m]
    #pragma unroll
    for (int i = 0; i < 2; ++i) {
      const int u0 = 16 * (wv + 4 * i);
      #pragma unroll
      for (int t = 0; t < 4; ++t)
        #pragma unroll
        for (int r = 0; r < 4; ++r) {
          const int m = 4 * q + r;
          const int d = m - n16 + 48 - 16 * t;
          const unsigned int dr = (unsigned int)(d - dbase);
          if (dr < 24u) scr[dr * ST + u0 + m] = acc[i][t][r] * scale;
        }
    }
    __syncthreads();
    // E2: full-line stores: 24 rows x 32 float4 (each 512B row = 4 full
    // 128B lines, written exactly once), non-temporal.
    const size_t obase = (((size_t)b * DD + dbase) * HH + h) * WW + w0;
    #pragma unroll
    for (int s3 = 0; s3 < 3; ++s3) {
      const int ss = tid + s3 * NT;
      const int dr = ss >> 5;
      const int p  = ss & 31;
      const f32x4 v = *reinterpret_cast<const f32x4*>(&scr[dr * ST + 4 * p]);
      __builtin_nontemporal_store(
          v, reinterpret_cast<f32x4*>(out + obase + (size_t)dr * HWs + 4 * p));
    }
  }
}

extern "C" void kernel_launch(void* const* d_in, const int* in_sizes, int n_in,
                              void* d_out, int out_size, void* d_ws, size_t ws_size,
                              hipStream_t stream) {
  const float* left  = (const float*)d_in[0];
  const float* right = (const float*)d_in[1];
  float* out = (float*)d_out;

  dim3 grid(WW / TW, HH, BB);   // 4 x 256 x 4 = 4096 blocks
  dim3 block(NT);
  cost_volume_mfma<<<grid, block, 0, stream>>>(left, right, out);
}